// Round 6
// baseline (34383.417 us; speedup 1.0000x reference)
//
#include <hip/hip_runtime.h>

// ROUND 6 — R5 module with fp32 I/O (single-variable change).
// Evidence: R5's absmax=NaN proves inputs are fp32 (bf16-misread mantissa
// halves produced Inf/NaN patterns); R5 also proved a minimal module launches
// cleanly, so the R1-R4 aborts live in the MFMA/workspace constructs, to be
// bisected in later rounds with timing data in hand.
// One kernel, no MFMA, no workspace, fp32 accumulate, demod as post-scale.

// grid (512, 8) = (o, b), 256 threads; each thread computes 16 pixels.
__global__ __launch_bounds__(256) void conv_direct(
    const float* __restrict__ fm, const float* __restrict__ style,
    const float* __restrict__ w, float* __restrict__ out)
{
  const int o = blockIdx.x, b = blockIdx.y, tid = threadIdx.x;
  __shared__ float swm[4608];   // modulated filter for (b,o), flat = ci*9 + t
  __shared__ float red[4];
  const float gain = 0.014731391f;              // 1/sqrt(512*9)
  const float* wo = w + (size_t)o * 4608;
  const float* st = style + (size_t)b * 512;
  float ss = 0.f;
#pragma unroll
  for (int j = 0; j < 18; ++j) {
    int idx = j * 256 + tid;                    // ci = idx/9
    float v = wo[idx] * gain * st[idx / 9];
    swm[idx] = v;
    ss += v * v;
  }
#pragma unroll
  for (int off = 32; off > 0; off >>= 1) ss += __shfl_down(ss, off, 64);
  if ((tid & 63) == 0) red[tid >> 6] = ss;
  __syncthreads();
  const float sinv = rsqrtf(red[0] + red[1] + red[2] + red[3] + 1e-8f);

  const int y = tid >> 2, x0 = (tid & 3) * 16;
  float acc[16];
#pragma unroll
  for (int i = 0; i < 16; ++i) acc[i] = 0.f;

  const float* fb = fm + (size_t)b * 512 * 4096;   // fm[b][ci][y][x]
  for (int ci = 0; ci < 512; ++ci) {
    const float* fc = fb + (size_t)ci * 4096;
    const float* wr = swm + ci * 9;
#pragma unroll
    for (int ky = 0; ky < 3; ++ky) {
      int yy = y + ky - 1;
      if (yy < 0 || yy > 63) continue;
      const float* frow = fc + yy * 64;
#pragma unroll
      for (int kx = 0; kx < 3; ++kx) {
        float wv = wr[ky * 3 + kx];
#pragma unroll
        for (int i = 0; i < 16; ++i) {
          int xx = x0 + i + kx - 1;
          float xv = (xx >= 0 && xx < 64) ? frow[xx] : 0.f;
          acc[i] += wv * xv;
        }
      }
    }
  }
  float* op = out + ((size_t)b * 512 + o) * 4096 + y * 64 + x0;
#pragma unroll
  for (int i = 0; i < 16; ++i) op[i] = acc[i] * sinv;  // demod post-scale (exact: linearity)
}

extern "C" void kernel_launch(void* const* d_in, const int* in_sizes, int n_in,
                              void* d_out, int out_size, void* d_ws, size_t ws_size,
                              hipStream_t stream) {
  const float* fm = (const float*)d_in[0];     // (8,512,64,64) fp32
  const float* style = (const float*)d_in[1];  // (8,512) fp32
  const float* w = (const float*)d_in[2];      // (512,512,3,3) fp32
  float* out = (float*)d_out;                  // (8,512,64,64) fp32
  (void)in_sizes; (void)n_in; (void)out_size; (void)d_ws; (void)ws_size;

  conv_direct<<<dim3(512, 8), 256, 0, stream>>>(fm, style, w, out);
}

// Round 7
// 424.292 us; speedup vs baseline: 81.0371x; 81.0371x over previous
//
#include <hip/hip_runtime.h>

typedef unsigned short u16;
typedef __attribute__((ext_vector_type(8))) short s16x8;   // 8 x bf16 (guide-verified frag type)
typedef __attribute__((ext_vector_type(4))) float floatx4;

// xt (per batch): [cg=16][row=66][col=66][c32=32] bf16, spatial-padded NCHW32c
#define XT_ROWELEMS 2112                 // 66*32
#define XT_CGELEMS  139392               // 66*66*32
#define XT_PB       4460544ull           // 16*66*66*32*2 bytes per batch
// wmod (per batch): [og=4][t=9][cg=16][o128=128][c32=32] bf16
#define WM_PB       4718592ull           // 4*9*16*128*32*2 bytes per batch

__device__ __forceinline__ u16 f2bf(float f) {
  union { float f; unsigned u; } x; x.f = f;
  unsigned r = x.u + 0x7fffu + ((x.u >> 16) & 1u);
  return (u16)(r >> 16);
}

// ---------------- kernel 1: fp32 NCHW -> padded NCHW32c bf16 ----------------
// grid (64, 16, nb) = (y, cg, b_local), 256 threads. Zeroes its own halo
// (no hipMemsetAsync needed).
__global__ __launch_bounds__(256) void transpose_nchw32(
    const float* __restrict__ fm, u16* __restrict__ xt, int b0)
{
  const int y = blockIdx.x, cg = blockIdx.y, bl = blockIdx.z, tid = threadIdx.x;
  __shared__ float sm[64 * 33];
  const int x = tid & 63, cq = tid >> 6;
  const float* src = fm + (((size_t)(b0 + bl) * 512 + cg * 32) * 64 + y) * 64;
#pragma unroll
  for (int j = 0; j < 8; ++j) {
    int ci = j * 4 + cq;
    sm[x * 33 + ci] = src[(size_t)ci * 4096 + x];   // coalesced along x
  }

  u16* cgbase = xt + (size_t)(bl * 16 + cg) * XT_CGELEMS;
  const uint4 z = {0u, 0u, 0u, 0u};
  // halo: col 0 + col 65 of this row (y+1)
  u16* rowb = cgbase + (size_t)(y + 1) * XT_ROWELEMS;
  if (tid < 4)              ((uint4*)rowb)[tid] = z;            // col 0 (32 bf16)
  else if (tid < 8)         ((uint4*)(rowb + 65 * 32))[tid - 4] = z;  // col 65
  // halo: full row 0 / row 65 (2112 bf16 = 264 uint4)
  if (y == 0)  for (int i = tid; i < 264; i += 256) ((uint4*)cgbase)[i] = z;
  if (y == 63) for (int i = tid; i < 264; i += 256) ((uint4*)(cgbase + 65 * XT_ROWELEMS))[i] = z;

  __syncthreads();
  u16* dst = rowb + 32;                             // interior cols 1..64
  union { u16 s[8]; uint4 v; } u;
#pragma unroll
  for (int j = 0; j < 8; ++j) {
    int e = tid * 8 + j;                            // e = x*32 + c32
    u.s[j] = f2bf(sm[(e >> 5) * 33 + (e & 31)]);
  }
  ((uint4*)dst)[tid] = u.v;                         // contiguous 4 KB per block
}

// ---------------- kernel 2: modulate + demodulate weights ----------------
// grid (512, nb) = (o, b_local), 256 threads.
__global__ __launch_bounds__(256) void modulate(
    const float* __restrict__ w, const float* __restrict__ style,
    u16* __restrict__ wm, int b0)
{
  const int o = blockIdx.x, bl = blockIdx.y, tid = threadIdx.x;
  __shared__ float sv[4608];
  __shared__ float red[4];
  const float gain = 0.014731391f;                  // 1/sqrt(512*9)
  const float* wo = w + (size_t)o * 4608;           // flat idx = ci*9 + t
  const float* st = style + (size_t)(b0 + bl) * 512;
  float ss = 0.f;
#pragma unroll
  for (int j = 0; j < 18; ++j) {
    int idx = j * 256 + tid;
    float v = wo[idx] * gain * st[idx / 9];
    sv[idx] = v;
    ss += v * v;
  }
#pragma unroll
  for (int off = 32; off > 0; off >>= 1) ss += __shfl_down(ss, off, 64);
  if ((tid & 63) == 0) red[tid >> 6] = ss;
  __syncthreads();
  float sinv = rsqrtf(red[0] + red[1] + red[2] + red[3] + 1e-8f);
  const int og = o >> 7, o128 = o & 127;
  u16* base = wm + ((size_t)((bl * 4 + og) * 9) * 16 * 128 + o128) * 32;
#pragma unroll
  for (int j = 0; j < 18; ++j) {
    int e = j * 256 + tid;                          // e = t*512 + c
    int t = e >> 9, c = e & 511;
    base[((size_t)(t * 16 + (c >> 5))) * 4096 + (c & 31)] = f2bf(sv[c * 9 + t] * sinv);
  }
}

// ---------------- kernel 3: implicit-GEMM conv via bf16 MFMA ----------------
// grid (32, 4, nb), 256 threads. C[o,p] 128x128 per block, K=4608.
// Register-staged (uint4 load -> ds_write), double-buffered A, B per cg.
__global__ __launch_bounds__(256, 2) void conv_mfma(
    const u16* __restrict__ Wmod, const u16* __restrict__ xt,
    float* __restrict__ out, int b0)
{
  const int p_blk = blockIdx.x, og = blockIdx.y, bl = blockIdx.z;
  const int tid = threadIdx.x;
  const int lane = tid & 63, wave = tid >> 6;
  const int wm_off = (wave & 1) * 64, wn_off = (wave >> 1) * 64;
  const int l15 = lane & 15, quad = lane >> 4;

  __shared__ __align__(16) u16 As[2][4096];         // [o128][c32], 8 KB x2
  __shared__ __align__(16) u16 Bs[8448];            // [r4][col66][c32], exact

  const int y0 = p_blk * 2;
  const size_t xt_base = ((size_t)(bl * 16) * XT_CGELEMS) + (size_t)y0 * XT_ROWELEMS;
  const size_t w_base = (size_t)((bl * 4 + og) * 9) * 16 * 4096;

  uint4 abuf[2], bbuf[5];
  auto load_b = [&](int cg) {                       // 1056 uint4 = 16896 B exact
    const uint4* g = (const uint4*)(xt + xt_base + (size_t)cg * XT_CGELEMS);
#pragma unroll
    for (int r = 0; r < 4; ++r) bbuf[r] = g[r * 256 + tid];
    if (tid < 32) bbuf[4] = g[1024 + tid];
  };
  auto write_b = [&]() {
#pragma unroll
    for (int r = 0; r < 4; ++r) ((uint4*)Bs)[r * 256 + tid] = bbuf[r];
    if (tid < 32) ((uint4*)Bs)[1024 + tid] = bbuf[4];
  };
  auto load_a = [&](int t, int cg) {                // 512 uint4 = 8192 B
    const uint4* g = (const uint4*)(Wmod + w_base + (size_t)(t * 16 + cg) * 4096);
#pragma unroll
    for (int r = 0; r < 2; ++r) abuf[r] = g[r * 256 + tid];
  };
  auto write_a = [&](int buf) {
#pragma unroll
    for (int r = 0; r < 2; ++r) ((uint4*)As[buf])[r * 256 + tid] = abuf[r];
  };

  floatx4 acc[4][4];
  const floatx4 zf = {0.f, 0.f, 0.f, 0.f};
#pragma unroll
  for (int mt = 0; mt < 4; ++mt)
#pragma unroll
    for (int nt = 0; nt < 4; ++nt) acc[mt][nt] = zf;

  load_b(0); write_b();
  load_a(0, 0); write_a(0);
  __syncthreads();

  for (int cg = 0; cg < 16; ++cg) {
    for (int t = 0; t < 9; ++t) {
      const int cur = (cg * 9 + t) & 1, nxt = cur ^ 1;
      const bool last = (cg == 15 && t == 8);
      const bool cgb = (t == 8 && cg < 15);         // cg boundary
      if (!last) load_a(t < 8 ? t + 1 : 0, t < 8 ? cg : cg + 1);  // reg prefetch
      if (cgb)   load_b(cg + 1);                    // reg prefetch (overlaps MFMA)

      const int ky = t / 3, kx = t - ky * 3;
      s16x8 afr[4], bfr[4];
      const u16* Ab = As[cur];
#pragma unroll
      for (int mt = 0; mt < 4; ++mt)                // A[m=lane&15][k=quad*8+j]
        afr[mt] = *(const s16x8*)&Ab[(wm_off + mt * 16 + l15) * 32 + quad * 8];
#pragma unroll
      for (int nt = 0; nt < 4; ++nt) {              // B[n=lane&15][k=quad*8+j]
        int p = wn_off + nt * 16 + l15;
        int r = (p >> 6) + ky, c = (p & 63) + kx;
        bfr[nt] = *(const s16x8*)&Bs[(r * 66 + c) * 32 + quad * 8];
      }
#pragma unroll
      for (int mt = 0; mt < 4; ++mt)
#pragma unroll
        for (int nt = 0; nt < 4; ++nt)
          acc[mt][nt] = __builtin_amdgcn_mfma_f32_16x16x32_bf16(
              afr[mt], bfr[nt], acc[mt][nt], 0, 0, 0);

      if (cgb) __syncthreads();                     // all waves done reading Bs
      if (!last) write_a(nxt);
      if (cgb)   write_b();
      __syncthreads();                              // staged LDS visible next step
    }
  }

  // epilogue: C/D layout col=lane&15, row=quad*4+reg (m89-verified); fp32 out
  float* outp = out + ((size_t)(b0 + bl) * 512 + og * 128) * 4096 + p_blk * 128;
#pragma unroll
  for (int mt = 0; mt < 4; ++mt)
#pragma unroll
    for (int nt = 0; nt < 4; ++nt) {
      int n = wn_off + nt * 16 + l15;
#pragma unroll
      for (int r = 0; r < 4; ++r) {
        int m = wm_off + mt * 16 + quad * 4 + r;
        outp[(size_t)m * 4096 + n] = acc[mt][nt][r];
      }
    }
}

// ---------------- fallback: zero-workspace direct conv (R6, known-PASS) ----------------
__global__ __launch_bounds__(256) void conv_direct(
    const float* __restrict__ fm, const float* __restrict__ style,
    const float* __restrict__ w, float* __restrict__ out)
{
  const int o = blockIdx.x, b = blockIdx.y, tid = threadIdx.x;
  __shared__ float swm[4608];
  __shared__ float red[4];
  const float gain = 0.014731391f;
  const float* wo = w + (size_t)o * 4608;
  const float* st = style + (size_t)b * 512;
  float ss = 0.f;
#pragma unroll
  for (int j = 0; j < 18; ++j) {
    int idx = j * 256 + tid;
    float v = wo[idx] * gain * st[idx / 9];
    swm[idx] = v;
    ss += v * v;
  }
#pragma unroll
  for (int off = 32; off > 0; off >>= 1) ss += __shfl_down(ss, off, 64);
  if ((tid & 63) == 0) red[tid >> 6] = ss;
  __syncthreads();
  const float sinv = rsqrtf(red[0] + red[1] + red[2] + red[3] + 1e-8f);

  const int y = tid >> 2, x0 = (tid & 3) * 16;
  float acc[16];
#pragma unroll
  for (int i = 0; i < 16; ++i) acc[i] = 0.f;
  const float* fb = fm + (size_t)b * 512 * 4096;
  for (int ci = 0; ci < 512; ++ci) {
    const float* fc = fb + (size_t)ci * 4096;
    const float* wr = swm + ci * 9;
#pragma unroll
    for (int ky = 0; ky < 3; ++ky) {
      int yy = y + ky - 1;
      if (yy < 0 || yy > 63) continue;
      const float* frow = fc + yy * 64;
#pragma unroll
      for (int kx = 0; kx < 3; ++kx) {
        float wv = wr[ky * 3 + kx];
#pragma unroll
        for (int i = 0; i < 16; ++i) {
          int xx = x0 + i + kx - 1;
          float xv = (xx >= 0 && xx < 64) ? frow[xx] : 0.f;
          acc[i] += wv * xv;
        }
      }
    }
  }
  float* op = out + ((size_t)b * 512 + o) * 4096 + y * 64 + x0;
#pragma unroll
  for (int i = 0; i < 16; ++i) op[i] = acc[i] * sinv;
}

extern "C" void kernel_launch(void* const* d_in, const int* in_sizes, int n_in,
                              void* d_out, int out_size, void* d_ws, size_t ws_size,
                              hipStream_t stream) {
  const float* fm = (const float*)d_in[0];     // (8,512,64,64) fp32
  const float* style = (const float*)d_in[1];  // (8,512) fp32
  const float* w = (const float*)d_in[2];      // (512,512,3,3) fp32
  float* out = (float*)d_out;                  // (8,512,64,64) fp32

  if (ws_size < XT_PB + WM_PB) {               // workspace too small: direct path
    conv_direct<<<dim3(512, 8), 256, 0, stream>>>(fm, style, w, out);
    return;
  }
  int nb = 8;
  while (nb > 1 && (size_t)nb * (XT_PB + WM_PB) > ws_size) nb >>= 1;

  u16* xt = (u16*)d_ws;
  u16* wmod = (u16*)((char*)d_ws + (size_t)nb * XT_PB);

  for (int b0 = 0; b0 < 8; b0 += nb) {
    transpose_nchw32<<<dim3(64, 16, nb), 256, 0, stream>>>(fm, xt, b0);
    modulate<<<dim3(512, nb), 256, 0, stream>>>(w, style, wmod, b0);
    conv_mfma<<<dim3(32, 4, nb), 256, 0, stream>>>(wmod, xt, out, b0);
  }
}

// Round 8
// 317.282 us; speedup vs baseline: 108.3687x; 1.3373x over previous
//
#include <hip/hip_runtime.h>

typedef unsigned short u16;
typedef __attribute__((ext_vector_type(8))) short s16x8;   // 8 x bf16 frag (verified form)
typedef __attribute__((ext_vector_type(4))) float floatx4;

// xt (per batch): [cg=16][row=66][col=66][c32=32] bf16, spatial-padded NCHW32c
#define XT_ROWELEMS 2112                 // 66*32
#define XT_CGELEMS  139392               // 66*66*32
#define XT_PB       4460544ull           // 16*66*66*32*2 bytes per batch
// wmod (per batch): [og=4][t=9][cg=16][o128=128][c32=32] bf16
#define WM_PB       4718592ull           // 4*9*16*128*32*2 bytes per batch

// async global->LDS DMA, 16B per lane; lds dest = wave-uniform base + lane*16
#define GLDS(gp, lp) __builtin_amdgcn_global_load_lds(                      \
    (const __attribute__((address_space(1))) void*)(gp),                    \
    (__attribute__((address_space(3))) void*)(lp), 16, 0, 0)

__device__ __forceinline__ u16 f2bf(float f) {
  union { float f; unsigned u; } x; x.f = f;
  unsigned r = x.u + 0x7fffu + ((x.u >> 16) & 1u);
  return (u16)(r >> 16);
}

// ---------------- kernel 1: fp32 NCHW -> padded NCHW32c bf16 ----------------
// grid (64, 16, nb), 256 threads. Zeroes its own halo.
__global__ __launch_bounds__(256) void transpose_nchw32(
    const float* __restrict__ fm, u16* __restrict__ xt, int b0)
{
  const int y = blockIdx.x, cg = blockIdx.y, bl = blockIdx.z, tid = threadIdx.x;
  __shared__ float sm[64 * 33];
  const int x = tid & 63, cq = tid >> 6;
  const float* src = fm + (((size_t)(b0 + bl) * 512 + cg * 32) * 64 + y) * 64;
#pragma unroll
  for (int j = 0; j < 8; ++j) {
    int ci = j * 4 + cq;
    sm[x * 33 + ci] = src[(size_t)ci * 4096 + x];   // coalesced along x
  }

  u16* cgbase = xt + (size_t)(bl * 16 + cg) * XT_CGELEMS;
  const uint4 z = {0u, 0u, 0u, 0u};
  u16* rowb = cgbase + (size_t)(y + 1) * XT_ROWELEMS;
  if (tid < 4)              ((uint4*)rowb)[tid] = z;                  // col 0
  else if (tid < 8)         ((uint4*)(rowb + 65 * 32))[tid - 4] = z;  // col 65
  if (y == 0)  for (int i = tid; i < 264; i += 256) ((uint4*)cgbase)[i] = z;
  if (y == 63) for (int i = tid; i < 264; i += 256) ((uint4*)(cgbase + 65 * XT_ROWELEMS))[i] = z;

  __syncthreads();
  u16* dst = rowb + 32;                             // interior cols 1..64
  union { u16 s[8]; uint4 v; } u;
#pragma unroll
  for (int j = 0; j < 8; ++j) {
    int e = tid * 8 + j;                            // e = x*32 + c32
    u.s[j] = f2bf(sm[(e >> 5) * 33 + (e & 31)]);
  }
  ((uint4*)dst)[tid] = u.v;
}

// ---------------- kernel 2: modulate + demodulate weights ----------------
// grid (512, nb), 256 threads.
__global__ __launch_bounds__(256) void modulate(
    const float* __restrict__ w, const float* __restrict__ style,
    u16* __restrict__ wm, int b0)
{
  const int o = blockIdx.x, bl = blockIdx.y, tid = threadIdx.x;
  __shared__ float sv[4608];
  __shared__ float red[4];
  const float gain = 0.014731391f;                  // 1/sqrt(512*9)
  const float* wo = w + (size_t)o * 4608;           // flat idx = ci*9 + t
  const float* st = style + (size_t)(b0 + bl) * 512;
  float ss = 0.f;
#pragma unroll
  for (int j = 0; j < 18; ++j) {
    int idx = j * 256 + tid;
    float v = wo[idx] * gain * st[idx / 9];
    sv[idx] = v;
    ss += v * v;
  }
#pragma unroll
  for (int off = 32; off > 0; off >>= 1) ss += __shfl_down(ss, off, 64);
  if ((tid & 63) == 0) red[tid >> 6] = ss;
  __syncthreads();
  float sinv = rsqrtf(red[0] + red[1] + red[2] + red[3] + 1e-8f);
  const int og = o >> 7, o128 = o & 127;
  u16* base = wm + ((size_t)((bl * 4 + og) * 9) * 16 * 128 + o128) * 32;
#pragma unroll
  for (int j = 0; j < 18; ++j) {
    int e = j * 256 + tid;                          // e = t*512 + c
    int t = e >> 9, c = e & 511;
    base[((size_t)(t * 16 + (c >> 5))) * 4096 + (c & 31)] = f2bf(sv[c * 9 + t] * sinv);
  }
}

// ---------------- kernel 3: implicit-GEMM conv via bf16 MFMA ----------------
// grid 32*4*nb linear, 256 threads. C[o,p] 128x128 per block, K=4608.
// global_load_lds staging (m97 pattern), dbuf A, single Bs restaged per cg.
// Swizzle: bl = id % nb -> same batch shares an XCD (round-robin dispatch).
__global__ __launch_bounds__(256, 3) void conv_mfma(
    const u16* __restrict__ Wmod, const u16* __restrict__ xt,
    float* __restrict__ out, int b0, int nb)
{
  const int id = blockIdx.x;
  const int bl = id % nb;
  const int rest = id / nb;
  const int og = rest & 3, p_blk = rest >> 2;
  const int tid = threadIdx.x;
  const int lane = tid & 63, wave = tid >> 6;
  const int wm_off = (wave & 1) * 64, wn_off = (wave >> 1) * 64;
  const int l15 = lane & 15, quad = lane >> 4;

  __shared__ __align__(16) u16 As[2][4096];         // [o128][c32], 8 KB x2
  __shared__ __align__(16) u16 Bs[8448];            // [r4][col66][c32] = 16896 B

  const int y0 = p_blk * 2;
  const size_t xt_base = ((size_t)(bl * 16) * XT_CGELEMS) + (size_t)y0 * XT_ROWELEMS;
  const size_t w_base = (size_t)((bl * 4 + og) * 9) * 16 * 4096;

  auto stage_b = [&](int cg) {                      // 16896 B contiguous, async
    const char* g = (const char*)(xt + xt_base + (size_t)cg * XT_CGELEMS);
    for (int r = wave; r < 16; r += 4)
      GLDS(g + r * 1024 + lane * 16, (char*)Bs + r * 1024);
    if (wave == 0 && lane < 32)                     // 512 B tail
      GLDS(g + 16384 + lane * 16, (char*)Bs + 16384);
  };
  auto stage_a = [&](int t, int cg, int buf) {      // 8192 B contiguous, async
    const char* g = (const char*)(Wmod + w_base + (size_t)(t * 16 + cg) * 4096);
    for (int r = wave; r < 8; r += 4)
      GLDS(g + r * 1024 + lane * 16, (char*)As[buf] + r * 1024);
  };

  floatx4 acc[4][4];
  const floatx4 zf = {0.f, 0.f, 0.f, 0.f};
#pragma unroll
  for (int mt = 0; mt < 4; ++mt)
#pragma unroll
    for (int nt = 0; nt < 4; ++nt) acc[mt][nt] = zf;

  stage_b(0);
  stage_a(0, 0, 0);
  __syncthreads();                                  // vmcnt drain -> data visible

  for (int cg = 0; cg < 16; ++cg) {
    for (int t = 0; t < 9; ++t) {
      const int cur = (cg * 9 + t) & 1, nxt = cur ^ 1;
      const bool last = (cg == 15 && t == 8);
      const bool cgb = (t == 8 && cg < 15);         // cg boundary
      if (!last) stage_a(t < 8 ? t + 1 : 0, t < 8 ? cg : cg + 1, nxt);  // async prefetch

      const int ky = t / 3, kx = t - ky * 3;
      s16x8 afr[4], bfr[4];
      const u16* Ab = As[cur];
#pragma unroll
      for (int mt = 0; mt < 4; ++mt)                // A[m=lane&15][k=quad*8+j]
        afr[mt] = *(const s16x8*)&Ab[(wm_off + mt * 16 + l15) * 32 + quad * 8];
#pragma unroll
      for (int nt = 0; nt < 4; ++nt) {              // B[n=lane&15][k=quad*8+j]
        int p = wn_off + nt * 16 + l15;
        int r = (p >> 6) + ky, c = (p & 63) + kx;
        bfr[nt] = *(const s16x8*)&Bs[(r * 66 + c) * 32 + quad * 8];
      }
#pragma unroll
      for (int mt = 0; mt < 4; ++mt)
#pragma unroll
        for (int nt = 0; nt < 4; ++nt)
          acc[mt][nt] = __builtin_amdgcn_mfma_f32_16x16x32_bf16(
              afr[mt], bfr[nt], acc[mt][nt], 0, 0, 0);

      if (cgb) {
        __syncthreads();                            // all waves done reading Bs
        stage_b(cg + 1);                            // async restage
      }
      __syncthreads();                              // drains DMA; LDS visible
    }
  }

  // epilogue: C/D layout col=lane&15, row=quad*4+reg (m89-verified)
  float* outp = out + ((size_t)(b0 + bl) * 512 + og * 128) * 4096 + p_blk * 128;
#pragma unroll
  for (int mt = 0; mt < 4; ++mt)
#pragma unroll
    for (int nt = 0; nt < 4; ++nt) {
      int n = wn_off + nt * 16 + l15;
#pragma unroll
      for (int r = 0; r < 4; ++r) {
        int m = wm_off + mt * 16 + quad * 4 + r;
        outp[(size_t)m * 4096 + n] = acc[mt][nt][r];
      }
    }
}

// ---------------- fallback: zero-workspace direct conv (R6, known-PASS) ----------------
__global__ __launch_bounds__(256) void conv_direct(
    const float* __restrict__ fm, const float* __restrict__ style,
    const float* __restrict__ w, float* __restrict__ out)
{
  const int o = blockIdx.x, b = blockIdx.y, tid = threadIdx.x;
  __shared__ float swm[4608];
  __shared__ float red[4];
  const float gain = 0.014731391f;
  const float* wo = w + (size_t)o * 4608;
  const float* st = style + (size_t)b * 512;
  float ss = 0.f;
#pragma unroll
  for (int j = 0; j < 18; ++j) {
    int idx = j * 256 + tid;
    float v = wo[idx] * gain * st[idx / 9];
    swm[idx] = v;
    ss += v * v;
  }
#pragma unroll
  for (int off = 32; off > 0; off >>= 1) ss += __shfl_down(ss, off, 64);
  if ((tid & 63) == 0) red[tid >> 6] = ss;
  __syncthreads();
  const float sinv = rsqrtf(red[0] + red[1] + red[2] + red[3] + 1e-8f);

  const int y = tid >> 2, x0 = (tid & 3) * 16;
  float acc[16];
#pragma unroll
  for (int i = 0; i < 16; ++i) acc[i] = 0.f;
  const float* fb = fm + (size_t)b * 512 * 4096;
  for (int ci = 0; ci < 512; ++ci) {
    const float* fc = fb + (size_t)ci * 4096;
    const float* wr = swm + ci * 9;
#pragma unroll
    for (int ky = 0; ky < 3; ++ky) {
      int yy = y + ky - 1;
      if (yy < 0 || yy > 63) continue;
      const float* frow = fc + yy * 64;
#pragma unroll
      for (int kx = 0; kx < 3; ++kx) {
        float wv = wr[ky * 3 + kx];
#pragma unroll
        for (int i = 0; i < 16; ++i) {
          int xx = x0 + i + kx - 1;
          float xv = (xx >= 0 && xx < 64) ? frow[xx] : 0.f;
          acc[i] += wv * xv;
        }
      }
    }
  }
  float* op = out + ((size_t)b * 512 + o) * 4096 + y * 64 + x0;
#pragma unroll
  for (int i = 0; i < 16; ++i) op[i] = acc[i] * sinv;
}

extern "C" void kernel_launch(void* const* d_in, const int* in_sizes, int n_in,
                              void* d_out, int out_size, void* d_ws, size_t ws_size,
                              hipStream_t stream) {
  const float* fm = (const float*)d_in[0];     // (8,512,64,64) fp32
  const float* style = (const float*)d_in[1];  // (8,512) fp32
  const float* w = (const float*)d_in[2];      // (512,512,3,3) fp32
  float* out = (float*)d_out;                  // (8,512,64,64) fp32

  if (ws_size < XT_PB + WM_PB) {               // workspace too small: direct path
    conv_direct<<<dim3(512, 8), 256, 0, stream>>>(fm, style, w, out);
    return;
  }
  int nb = 8;
  while (nb > 1 && (size_t)nb * (XT_PB + WM_PB) > ws_size) nb >>= 1;

  u16* xt = (u16*)d_ws;
  u16* wmod = (u16*)((char*)d_ws + (size_t)nb * XT_PB);

  for (int b0 = 0; b0 < 8; b0 += nb) {
    transpose_nchw32<<<dim3(64, 16, nb), 256, 0, stream>>>(fm, xt, b0);
    modulate<<<dim3(512, nb), 256, 0, stream>>>(w, style, wmod, b0);
    conv_mfma<<<dim3(32 * 4 * nb), 256, 0, stream>>>(wmod, xt, out, b0, nb);
  }
}